// Round 1
// 33.181 us; speedup vs baseline: 1.2594x; 1.2594x over previous
//
#include <hip/hip_runtime.h>
#include <math.h>

#define TPB 256
#define MPB (TPB * 2)   // 2 matrices per thread, paired in float2 lanes

typedef float v2  __attribute__((ext_vector_type(2)));
typedef int   v2i __attribute__((ext_vector_type(2)));

static __device__ __forceinline__ v2 V2(float x){ v2 r; r.x = x; r.y = x; return r; }
static __device__ __forceinline__ v2 vfma(v2 a, v2 b, v2 c){ return __builtin_elementwise_fma(a, b, c); }
static __device__ __forceinline__ v2 vmax(v2 a, v2 b){ return __builtin_elementwise_max(a, b); }
static __device__ __forceinline__ v2 vabs(v2 a){ return __builtin_elementwise_abs(a); }
static __device__ __forceinline__ v2 vcps(v2 a, v2 b){ return __builtin_elementwise_copysign(a, b); }

// per-component transcendentals (no packed variants exist; quarter-rate pipe)
static __device__ __forceinline__ v2 rsq2(v2 x){ v2 r; r.x = __builtin_amdgcn_rsqf(x.x);  r.y = __builtin_amdgcn_rsqf(x.y);  return r; }
static __device__ __forceinline__ v2 rcp2(v2 x){ v2 r; r.x = __builtin_amdgcn_rcpf(x.x);  r.y = __builtin_amdgcn_rcpf(x.y);  return r; }
static __device__ __forceinline__ v2 sqt2(v2 x){ v2 r; r.x = __builtin_amdgcn_sqrtf(x.x); r.y = __builtin_amdgcn_sqrtf(x.y); return r; }
static __device__ __forceinline__ v2 lg22(v2 x){ v2 r; r.x = __builtin_amdgcn_logf(x.x);  r.y = __builtin_amdgcn_logf(x.y);  return r; }
static __device__ __forceinline__ v2 ex22(v2 x){ v2 r; r.x = __builtin_amdgcn_exp2f(x.x); r.y = __builtin_amdgcn_exp2f(x.y); return r; }

// elementwise select: m ? a : b  (m is -1/0 per component from a vector compare)
static __device__ __forceinline__ v2 vsel(v2i m, v2 a, v2 b){
  v2i ai = __builtin_bit_cast(v2i, a), bi = __builtin_bit_cast(v2i, b);
  return __builtin_bit_cast(v2, (ai & m) | (bi & ~m));
}

// Exact Jacobi rotation for [[app,apq],[apq,aqq]] via half-angle form.
// Identical arithmetic (and op order) to the scalar version; 2 rsqrt each.
__device__ __forceinline__ void jcs2(v2 app_in, v2 aqq_in, v2 apq,
                                     v2& c, v2& s,
                                     v2& app_out, v2& aqq_out)
{
  v2 d    = (aqq_in - app_in) * 0.5f;
  v2 r2   = vmax(vfma(d, d, apq * apq), V2(1e-60f));
  v2 invh = rsq2(r2);
  v2 h    = r2 * invh;                       // sqrt(d^2 + apq^2)
  v2 sg   = vcps(V2(1.0f), d);
  v2 ch   = h + vabs(d);
  v2 sh   = apq * sg;
  v2 w    = rsq2(vfma(ch, ch, sh * sh));
  c = ch * w;
  s = sh * w;
  v2 hs = h * sg;
  v2 m  = app_in + d;                        // (app+aqq)/2
  app_out = m - hs;
  aqq_out = m + hs;
}

// Full rotation: diag (closed form), third-index couplings, V columns p,q.
__device__ __forceinline__ void jrot(v2& app, v2& aqq, v2& apq,
                                     v2& apk, v2& aqk,
                                     v2& vp0, v2& vp1, v2& vp2,
                                     v2& vq0, v2& vq1, v2& vq2)
{
  v2 c, s;
  jcs2(app, aqq, apq, c, s, app, aqq);   // inputs by value: aliasing safe
  apq = V2(0.0f);
  v2 pk = apk, qk = aqk;
  apk = c * pk - s * qk;
  aqk = s * pk + c * qk;
  v2 v;
  v = vp0; vp0 = c*v - s*vq0; vq0 = s*v + c*vq0;
  v = vp1; vp1 = c*v - s*vq1; vq1 = s*v + c*vq1;
  v = vp2; vp2 = c*v - s*vq2; vq2 = s*v + c*vq2;
}

// Compare-swap: per-component (the two matrices in a thread sort independently).
#define CSWAP(li, lj, a0, a1, a2, b0, b1, b2)                                   \
  do {                                                                          \
    v2i _m = (li) < (lj);                                                       \
    v2 _t;                                                                      \
    _t = vsel(_m,(lj),(li)); (lj) = vsel(_m,(li),(lj)); (li) = _t;              \
    _t = vsel(_m,(b0),(a0)); (b0) = vsel(_m,(a0),(b0)); (a0) = _t;              \
    _t = vsel(_m,(b1),(a1)); (b1) = vsel(_m,(a1),(b1)); (a1) = _t;              \
    _t = vsel(_m,(b2),(a2)); (b2) = vsel(_m,(a2),(b2)); (a2) = _t;              \
  } while (0)

__global__ __launch_bounds__(TPB) void plastic_svd_kernel(
    const float* __restrict__ F,
    const float* __restrict__ p_yml,
    const float* __restrict__ p_nu,
    const float* __restrict__ p_ys,
    float* __restrict__ out,
    int nmat)
{
  __shared__ float lds[MPB * 9];
  const int tid = threadIdx.x;
  const int blockBase = blockIdx.x * MPB;
  const int gbase = blockBase * 9;
  const int rem = nmat - blockBase;
  const int nfl = (rem >= MPB ? MPB : rem) * 9;
  const int nfl4 = nfl >> 2;

  // coalesced global -> LDS stage, float4-wide (gbase*4 bytes is 16B-aligned)
  {
    const float4* g4 = (const float4*)(F + gbase);
    float4* l4 = (float4*)lds;
    #pragma unroll
    for (int k = 0; k < 5; ++k) {            // 5*256 = 1280 >= 4608/4 = 1152
      int i4 = k * TPB + tid;
      if (i4 < nfl4) l4[i4] = g4[i4];
    }
    int i = (nfl & ~3) + tid;
    if (i < nfl) lds[i] = F[gbase + i];      // scalar tail (<=3 elems)
    // zero-fill inactive tail (last block only): keeps math NaN-free w/o
    // per-component predication on the register loads.
    for (int i2 = nfl + tid; i2 < MPB * 9; i2 += TPB) lds[i2] = 0.0f;
  }
  __syncthreads();

  const int mi0 = blockBase + tid;          // lane .x matrix
  const int mi1 = blockBase + TPB + tid;    // lane .y matrix
  // chunk ownership is exclusive per-thread (read own chunks, later write own
  // chunks) -> no barrier needed between the register load and the LDS
  // output write; only the pre-store barrier below is required.
  const float* mA = &lds[tid * 9];
  const float* mB = &lds[(tid + TPB) * 9];
  v2 f00,f01,f02,f10,f11,f12,f20,f21,f22;
  f00.x=mA[0]; f01.x=mA[1]; f02.x=mA[2];
  f10.x=mA[3]; f11.x=mA[4]; f12.x=mA[5];
  f20.x=mA[6]; f21.x=mA[7]; f22.x=mA[8];
  f00.y=mB[0]; f01.y=mB[1]; f02.y=mB[2];
  f10.y=mB[3]; f11.y=mB[4]; f12.y=mB[5];
  f20.y=mB[6]; f21.y=mB[7]; f22.y=mB[8];

  // uniform scalar parameters (once per thread, amortized over 2 matrices)
  const float mu_s = __builtin_amdgcn_exp2f(p_yml[0] * 1.44269504f) *
                     __builtin_amdgcn_rcpf(2.0f * (1.0f + p_nu[0]));
  const float qy_s = p_ys[0] * 0.5f * __builtin_amdgcn_rcpf(mu_s);
  const v2 qy = V2(qy_s);

  // S = F^T F (symmetric)
  v2 s00 = f00*f00 + f10*f10 + f20*f20;
  v2 s11 = f01*f01 + f11*f11 + f21*f21;
  v2 s22 = f02*f02 + f12*f12 + f22*f22;
  v2 s01 = f00*f01 + f10*f11 + f20*f21;
  v2 s02 = f00*f02 + f10*f12 + f20*f22;
  v2 s12 = f01*f02 + f11*f12 + f21*f22;

  v2 v00,v01,v02,v10,v11,v12,v20,v21,v22;
  v2 c, s;

  // ---- sweep 1, rot (0,1): V = I specialization ----
  jcs2(s00, s11, s01, c, s, s00, s11);
  { v2 pk = s02, qk = s12; s02 = c*pk - s*qk; s12 = s*pk + c*qk; }
  v00 = c;  v01 = s;
  v10 = -s; v11 = c;
  s01 = V2(0.0f);
  // ---- sweep 1, rot (0,2): col2 still e3, col0 = (v00,v10,0) ----
  jcs2(s00, s22, s02, c, s, s00, s22);
  { v2 pk = s01, qk = s12; s01 = c*pk - s*qk; s12 = s*pk + c*qk; }
  v02 = s * v00; v12 = s * v10; v22 = c;   // vq' = s*vp + c*e3 (old vp)
  v00 = c * v00; v10 = c * v10; v20 = -s;  // vp' = c*vp - s*e3
  v21 = V2(0.0f);
  s02 = V2(0.0f);
  // ---- sweep 1, rot (1,2) ----
  jrot(s11, s22, s12, s01, s02, v01, v11, v21, v02, v12, v22);
  // ---- sweep 2 ----
  jrot(s00, s11, s01, s02, s12, v00, v10, v20, v01, v11, v21);
  jrot(s00, s22, s02, s01, s12, v00, v10, v20, v02, v12, v22);
  jrot(s11, s22, s12, s01, s02, v01, v11, v21, v02, v12, v22);
  // ---- sweep 3 ----
  jrot(s00, s11, s01, s02, s12, v00, v10, v20, v01, v11, v21);
  jrot(s00, s22, s02, s01, s12, v00, v10, v20, v02, v12, v22);
  // final rot (1,2): couplings dead; diag still updated for the sort below.
  jcs2(s11, s22, s12, c, s, s11, s22);
  { v2 v;
    v = v01; v01 = c*v - s*v02; v02 = s*v + c*v02;
    v = v11; v11 = c*v - s*v12; v12 = s*v + c*v12;
    v = v21; v21 = c*v - s*v22; v22 = s*v + c*v22; }

  // ---- sort eigenvalues descending, V columns along ----
  v2 l0 = s00, l1 = s11, l2 = s22;
  CSWAP(l0, l1, v00, v10, v20, v01, v11, v21);
  CSWAP(l1, l2, v01, v11, v21, v02, v12, v22);
  CSWAP(l0, l1, v00, v10, v20, v01, v11, v21);

  // ---- U construction: u0 = Fv0/|Fv0|; u1 = GS; u2 = u0 x u1 (sign-fixed) ----
  v2 w0x = f00*v00 + f01*v10 + f02*v20;
  v2 w0y = f10*v00 + f11*v10 + f12*v20;
  v2 w0z = f20*v00 + f21*v10 + f22*v20;
  v2 n0sq = w0x*w0x + w0y*w0y + w0z*w0z;
  v2 inv0 = rsq2(vmax(n0sq, V2(1e-40f)));
  v2 sig0 = n0sq * inv0;                 // = sqrt(n0sq)
  v2 u0x = w0x*inv0, u0y = w0y*inv0, u0z = w0z*inv0;

  v2 w1x = f00*v01 + f01*v11 + f02*v21;
  v2 w1y = f10*v01 + f11*v11 + f12*v21;
  v2 w1z = f20*v01 + f21*v11 + f22*v21;
  v2 sig1 = sqt2(w1x*w1x + w1y*w1y + w1z*w1z);   // pre-GS norm = sigma1
  v2 d01 = w1x*u0x + w1y*u0y + w1z*u0z;
  w1x = w1x - d01*u0x; w1y = w1y - d01*u0y; w1z = w1z - d01*u0z;
  v2 n1sq = w1x*w1x + w1y*w1y + w1z*w1z;
  v2 inv1 = rsq2(vmax(n1sq, V2(1e-40f)));
  v2 u1x = w1x*inv1, u1y = w1y*inv1, u1z = w1z*inv1;

  v2 u2x = u0y*u1z - u0z*u1y;
  v2 u2y = u0z*u1x - u0x*u1z;
  v2 u2z = u0x*u1y - u0y*u1x;
  v2 w2x = f00*v02 + f01*v12 + f02*v22;
  v2 w2y = f10*v02 + f11*v12 + f12*v22;
  v2 w2z = f20*v02 + f21*v12 + f22*v22;
  v2 s2d = u2x*w2x + u2y*w2y + u2z*w2z;
  v2i _neg = s2d < V2(0.0f);
  v2 sg = vsel(_neg, V2(-1.0f), V2(1.0f));
  v2 sig2 = s2d * sg;
  u2x = u2x * sg; u2y = u2y * sg; u2z = u2z * sg;

  // ---- von-Mises return mapping, base-2 internally ----
  v2 c0 = vmax(sig0, V2(0.01f));
  v2 c1 = vmax(sig1, V2(0.01f));
  v2 c2 = vmax(sig2, V2(0.01f));
  v2 e0 = lg22(c0), e1 = lg22(c1), e2 = lg22(c2);
  v2 m3 = (e0 + e1 + e2) * (1.0f / 3.0f);
  v2 b0 = e0 - m3, b1 = e1 - m3, b2 = e2 - m3;
  // ||dev eps||_ln = ln2 * ||b||_log2 ; +NORM_EPS in ln units
  v2 bn = sqt2(b0*b0 + b1*b1 + b2*b2) * 0.69314718f + V2(1e-5f);
  v2 r = vmax(bn - qy, V2(0.0f)) * rcp2(bn);  // 0 if elastic
  c0 = ex22(e0 - r * b0);
  c1 = ex22(e1 - r * b1);
  c2 = ex22(e2 - r * b2);

  // ---- out = sum_i c_i u_i v_i^T ----
  v2 a0x = c0*u0x, a0y = c0*u0y, a0z = c0*u0z;
  v2 a1x = c1*u1x, a1y = c1*u1y, a1z = c1*u1z;
  v2 a2x = c2*u2x, a2y = c2*u2y, a2z = c2*u2z;

  v2 o00 = a0x*v00 + a1x*v01 + a2x*v02;
  v2 o01 = a0x*v10 + a1x*v11 + a2x*v12;
  v2 o02 = a0x*v20 + a1x*v21 + a2x*v22;
  v2 o10 = a0y*v00 + a1y*v01 + a2y*v02;
  v2 o11 = a0y*v10 + a1y*v11 + a2y*v12;
  v2 o12 = a0y*v20 + a1y*v21 + a2y*v22;
  v2 o20 = a0z*v00 + a1z*v01 + a2z*v02;
  v2 o21 = a0z*v10 + a1z*v11 + a2z*v12;
  v2 o22 = a0z*v20 + a1z*v21 + a2z*v22;

  if (mi0 < nmat) {
    float* m = &lds[tid * 9];
    m[0]=o00.x; m[1]=o01.x; m[2]=o02.x;
    m[3]=o10.x; m[4]=o11.x; m[5]=o12.x;
    m[6]=o20.x; m[7]=o21.x; m[8]=o22.x;
  }
  if (mi1 < nmat) {
    float* m = &lds[(tid + TPB) * 9];
    m[0]=o00.y; m[1]=o01.y; m[2]=o02.y;
    m[3]=o10.y; m[4]=o11.y; m[5]=o12.y;
    m[6]=o20.y; m[7]=o21.y; m[8]=o22.y;
  }
  __syncthreads();

  // coalesced LDS -> global store, float4-wide
  {
    float4* g4 = (float4*)(out + gbase);
    const float4* l4 = (const float4*)lds;
    #pragma unroll
    for (int k = 0; k < 5; ++k) {
      int i4 = k * TPB + tid;
      if (i4 < nfl4) g4[i4] = l4[i4];
    }
    int i = (nfl & ~3) + tid;
    if (i < nfl) out[gbase + i] = lds[i];
  }
}

extern "C" void kernel_launch(void* const* d_in, const int* in_sizes, int n_in,
                              void* d_out, int out_size, void* d_ws, size_t ws_size,
                              hipStream_t stream) {
  const float* F     = (const float*)d_in[0];
  const float* p_yml = (const float*)d_in[1];
  const float* p_nu  = (const float*)d_in[2];
  const float* p_ys  = (const float*)d_in[3];
  float* out = (float*)d_out;

  const int nmat = in_sizes[0] / 9;
  const int nblocks = (nmat + MPB - 1) / MPB;
  hipLaunchKernelGGL(plastic_svd_kernel, dim3(nblocks), dim3(TPB), 0, stream,
                     F, p_yml, p_nu, p_ys, out, nmat);
}